// Round 1
// baseline (4283.748 us; speedup 1.0000x reference)
//
#include <hip/hip_runtime.h>
#include <stdint.h>

// ---------------- problem constants ----------------
#define T_TOK 4096   // B*S tokens
#define DM    2048   // d_model
#define DFF   8192   // expert ff
#define SFF   4096   // shared ff (2 shared experts concat -> one FF=8192 "expert 8")
#define MAXROWS 13312   // max padded grouped rows: <=71*128 expert + 4096 shared
#define MAXTILES 104    // worst-case M tiles: 71 expert + 32 shared + slack
#define BM 128
#define BN 128
#define BK 64

typedef __attribute__((ext_vector_type(8))) __bf16 bf16x8;
typedef __attribute__((ext_vector_type(2))) __bf16 bf16x2;
typedef __attribute__((ext_vector_type(4))) float f32x4;
typedef __attribute__((ext_vector_type(4))) unsigned int u32x4;

__device__ inline unsigned int pack2(float lo, float hi) {
  bf16x2 v = {(__bf16)lo, (__bf16)hi};   // RNE via v_cvt_pk_bf16_f32
  return __builtin_bit_cast(unsigned int, v);
}

__device__ inline void gload_lds16(const void* g, void* l) {
  __builtin_amdgcn_global_load_lds(
      (const __attribute__((address_space(1))) void*)g,
      (__attribute__((address_space(3))) void*)l, 16, 0, 0);
}

// ---------------- router: fp32 logits/softmax/top2/aux, bucket scatter ----------------
__global__ __launch_bounds__(256) void router_kernel(
    const float* __restrict__ x, const float* __restrict__ wg,
    float* __restrict__ scores_buf, float* __restrict__ lse_buf,
    int* __restrict__ bucket_tok, float* __restrict__ bucket_w, int* __restrict__ cursor)
{
  const int wave = threadIdx.x >> 6;
  const int lane = threadIdx.x & 63;
  const int t = blockIdx.x * 4 + wave;
  float a0=0,a1=0,a2=0,a3=0,a4=0,a5=0,a6=0,a7=0;
  const float* xr = x + (size_t)t * DM;
  for (int j = 0; j < 32; ++j) {
    const int d = lane + 64 * j;
    const float xv = xr[d];
    const float4* w = (const float4*)(wg + (size_t)d * 8);
    const float4 w0 = w[0], w1 = w[1];
    a0 += xv*w0.x; a1 += xv*w0.y; a2 += xv*w0.z; a3 += xv*w0.w;
    a4 += xv*w1.x; a5 += xv*w1.y; a6 += xv*w1.z; a7 += xv*w1.w;
  }
  for (int off = 32; off; off >>= 1) {
    a0 += __shfl_xor(a0, off); a1 += __shfl_xor(a1, off);
    a2 += __shfl_xor(a2, off); a3 += __shfl_xor(a3, off);
    a4 += __shfl_xor(a4, off); a5 += __shfl_xor(a5, off);
    a6 += __shfl_xor(a6, off); a7 += __shfl_xor(a7, off);
  }
  if (lane == 0) {
    float l[8] = {a0,a1,a2,a3,a4,a5,a6,a7};
    float m = l[0];
    #pragma unroll
    for (int e = 1; e < 8; ++e) m = fmaxf(m, l[e]);
    float ex[8]; float se = 0.f;
    #pragma unroll
    for (int e = 0; e < 8; ++e) { ex[e] = expf(l[e] - m); se += ex[e]; }
    const float lse = m + logf(se);
    lse_buf[t] = lse;
    float s[8]; const float inv = 1.0f / se;
    #pragma unroll
    for (int e = 0; e < 8; ++e) { s[e] = ex[e] * inv; scores_buf[t * 8 + e] = s[e]; }
    int i1 = 0; float s1 = s[0];
    #pragma unroll
    for (int e = 1; e < 8; ++e) if (s[e] > s1) { s1 = s[e]; i1 = e; }   // ties -> lower idx (jax)
    int i2 = -1; float s2 = -1.f;
    #pragma unroll
    for (int e = 0; e < 8; ++e) if (e != i1 && s[e] > s2) { s2 = s[e]; i2 = e; }
    const int p1 = atomicAdd(&cursor[i1], 1);
    bucket_tok[i1 * T_TOK + p1] = t; bucket_w[i1 * T_TOK + p1] = s1;
    const int p2 = atomicAdd(&cursor[i2], 1);
    bucket_tok[i2 * T_TOK + p2] = t; bucket_w[i2 * T_TOK + p2] = s2;
  }
}

// ---------------- plan: aux losses, bases, tile list, row->token map ----------------
__global__ __launch_bounds__(256) void plan_kernel(
    const float* __restrict__ scores_buf, const float* __restrict__ lse_buf,
    const int* __restrict__ cursor, const int* __restrict__ bucket_tok,
    const float* __restrict__ bucket_w,
    int2* __restrict__ tile_desc, int* __restrict__ ntiles_g,
    int* __restrict__ row_src, float* __restrict__ rows_weight,
    float* __restrict__ out_aux)
{
  __shared__ float redP[256][8];
  __shared__ float redZ[256];
  __shared__ int base_s[10];
  const int tid = threadIdx.x;
  float p[8] = {0,0,0,0,0,0,0,0}; float z = 0.f;
  for (int r = tid; r < T_TOK; r += 256) {
    #pragma unroll
    for (int e = 0; e < 8; ++e) p[e] += scores_buf[r * 8 + e];
    const float l = lse_buf[r]; z += l * l;
  }
  #pragma unroll
  for (int e = 0; e < 8; ++e) redP[tid][e] = p[e];
  redZ[tid] = z;
  __syncthreads();
  for (int st = 128; st; st >>= 1) {
    if (tid < st) {
      #pragma unroll
      for (int e = 0; e < 8; ++e) redP[tid][e] += redP[tid + st][e];
      redZ[tid] += redZ[tid + st];
    }
    __syncthreads();
  }
  if (tid == 0) {
    float aux = 0.f;
    for (int e = 0; e < 8; ++e) {
      const float f = (float)cursor[e] / (float)T_TOK;
      const float P = redP[0][e] / (float)T_TOK;
      aux += f * P;
    }
    aux *= 0.01f * 8.0f;                       // AUX_COEF * N_EXPERTS
    const float zl = 0.001f * (redZ[0] / (float)T_TOK);
    *out_aux = aux + zl;
    int nt = 0, tot = 0;
    for (int e = 0; e < 8; ++e) {
      base_s[e] = tot;
      const int cnt = cursor[e];
      const int ntl = (cnt + BM - 1) / BM;
      for (int i = 0; i < ntl; ++i) { tile_desc[nt] = make_int2(tot + i * BM, e); ++nt; }
      tot += ntl * BM;
    }
    base_s[8] = tot;
    for (int i = 0; i < 32; ++i) { tile_desc[nt] = make_int2(tot + i * BM, 8); ++nt; }
    tot += T_TOK;
    base_s[9] = tot;
    *ntiles_g = nt;
  }
  __syncthreads();
  for (int row = tid; row < MAXROWS; row += 256) {
    int tok = -1; float w = 0.f;
    if (row < base_s[9]) {
      if (row >= base_s[8]) { tok = row - base_s[8]; w = 1.0f; }   // shared pseudo-expert
      else {
        int e = 0;
        while (e < 7 && row >= base_s[e + 1]) ++e;
        const int i = row - base_s[e];
        if (i < cursor[e]) { tok = bucket_tok[e * T_TOK + i]; w = bucket_w[e * T_TOK + i]; }
      }
    }
    row_src[row] = tok;
    rows_weight[row] = w;
  }
}

// ---------------- gather: X rows -> grouped bf16 Xg (zero pad rows) ----------------
__global__ __launch_bounds__(256) void gather_kernel(
    const float* __restrict__ x, const int* __restrict__ row_src,
    unsigned short* __restrict__ Xg)
{
  const int row = blockIdx.x;
  const int tok = row_src[row];
  const int d = threadIdx.x * 8;
  u32x4 pk = {0u, 0u, 0u, 0u};
  if (tok >= 0) {
    const float* src = x + (size_t)tok * DM + d;
    const float4 a = *(const float4*)src;
    const float4 b = *(const float4*)(src + 4);
    pk[0] = pack2(a.x, a.y); pk[1] = pack2(a.z, a.w);
    pk[2] = pack2(b.x, b.y); pk[3] = pack2(b.z, b.w);
  }
  *(u32x4*)(Xg + (size_t)row * DM + d) = pk;
}

// ---------------- GEMM1: act = silu(Xg@W1) * (Xg@W2) for one FF slice ----------------
__global__ __launch_bounds__(256, 2) void gemm1_kernel(
    const unsigned short* __restrict__ Xg,
    const float* __restrict__ ew1, const float* __restrict__ ew2,
    const float* __restrict__ sw1, const float* __restrict__ sw2,
    const int2* __restrict__ tile_desc, const int* __restrict__ ntiles_g,
    unsigned short* __restrict__ Hact, int h, int halfsz)
{
  if ((int)blockIdx.x >= *ntiles_g) return;
  const int2 td = tile_desc[blockIdx.x];
  const int row0 = td.x;
  const int e = td.y;
  const int n0 = blockIdx.y * BN;
  const int fg0 = h * halfsz + n0;      // global FF column of this tile
  const float *b1, *b2;
  size_t ldb;
  if (e < 8) {
    ldb = DFF;
    const size_t off = (size_t)e * DM * DFF + fg0;
    b1 = ew1 + off; b2 = ew2 + off;
  } else {
    ldb = SFF;
    const size_t off = (size_t)(fg0 >> 12) * DM * SFF + (fg0 & 4095);
    b1 = sw1 + off; b2 = sw2 + off;
  }
  __shared__ __align__(16) char smem[49152];
  char* sA  = smem;
  char* sB1 = smem + 16384;
  char* sB2 = smem + 32768;
  const int tid  = threadIdx.x;
  const int lane = tid & 63;
  const int wv   = tid >> 6;
  const int wm   = (wv >> 1) * 64;
  const int wn   = (wv & 1) * 64;
  const f32x4 zero = {0.f, 0.f, 0.f, 0.f};
  f32x4 acc1[4][4], acc2[4][4];
  #pragma unroll
  for (int i = 0; i < 4; ++i)
    #pragma unroll
    for (int j = 0; j < 4; ++j) { acc1[i][j] = zero; acc2[i][j] = zero; }

  const unsigned short* Arow = Xg + (size_t)row0 * DM;
  const int aa = lane;   // n = 2*aa + no
  const int kg = wv;     // 16 k-rows per wave

  for (int kt = 0; kt < DM / BK; ++kt) {
    const int k0 = kt * BK;
    __syncthreads();
    // A: global_load_lds, source pre-swizzled so LDS layout = [row][kb ^ (row&7)]
    #pragma unroll
    for (int it = 0; it < 4; ++it) {
      const int idx = it * 256 + tid;
      const int row = idx >> 3;
      const int s   = idx & 7;
      const int kb  = s ^ (row & 7);
      gload_lds16(Arow + (size_t)row * DM + k0 + kb * 8, sA + idx * 16);
    }
    // B: reg-stage fp32 -> bf16, transposed LDS [n][k] with kb ^= (n>>1)&7
    {
      const float* p1 = b1 + (size_t)(k0 + kg * 16) * ldb + 2 * aa;
      const float* p2 = b2 + (size_t)(k0 + kg * 16) * ldb + 2 * aa;
      float2 v1[16], v2[16];
      #pragma unroll
      for (int j = 0; j < 16; ++j) v1[j] = *(const float2*)(p1 + (size_t)j * ldb);
      #pragma unroll
      for (int j = 0; j < 16; ++j) v2[j] = *(const float2*)(p2 + (size_t)j * ldb);
      #pragma unroll
      for (int b = 0; b < 2; ++b) {
        #pragma unroll
        for (int no = 0; no < 2; ++no) {
          const int n  = 2 * aa + no;
          const int kb = kg * 2 + b;
          const int s  = kb ^ ((n >> 1) & 7);
          unsigned int q1[4], q2[4];
          #pragma unroll
          for (int q = 0; q < 4; ++q) {
            const int j = b * 8 + 2 * q;
            q1[q] = no ? pack2(v1[j].y, v1[j + 1].y) : pack2(v1[j].x, v1[j + 1].x);
            q2[q] = no ? pack2(v2[j].y, v2[j + 1].y) : pack2(v2[j].x, v2[j + 1].x);
          }
          u32x4 t1 = {q1[0], q1[1], q1[2], q1[3]};
          u32x4 t2 = {q2[0], q2[1], q2[2], q2[3]};
          *(u32x4*)(sB1 + n * 128 + s * 16) = t1;
          *(u32x4*)(sB2 + n * 128 + s * 16) = t2;
        }
      }
    }
    __syncthreads();
    #pragma unroll
    for (int ks = 0; ks < 2; ++ks) {
      bf16x8 af[4], bq[4], br[4];
      const int kb = ks * 4 + (lane >> 4);
      #pragma unroll
      for (int m = 0; m < 4; ++m) {
        const int r = wm + m * 16 + (lane & 15);
        af[m] = *(const bf16x8*)(sA + r * 128 + (kb ^ (r & 7)) * 16);
      }
      #pragma unroll
      for (int n = 0; n < 4; ++n) {
        const int c = wn + n * 16 + (lane & 15);
        const int s = (kb ^ ((c >> 1) & 7)) * 16;
        bq[n] = *(const bf16x8*)(sB1 + c * 128 + s);
        br[n] = *(const bf16x8*)(sB2 + c * 128 + s);
      }
      #pragma unroll
      for (int m = 0; m < 4; ++m)
        #pragma unroll
        for (int n = 0; n < 4; ++n) {
          acc1[m][n] = __builtin_amdgcn_mfma_f32_16x16x32_bf16(af[m], bq[n], acc1[m][n], 0, 0, 0);
          acc2[m][n] = __builtin_amdgcn_mfma_f32_16x16x32_bf16(af[m], br[n], acc2[m][n], 0, 0, 0);
        }
    }
  }
  // epilogue: SwiGLU, store bf16 act tile
  #pragma unroll
  for (int m = 0; m < 4; ++m)
    #pragma unroll
    for (int n = 0; n < 4; ++n)
      #pragma unroll
      for (int q = 0; q < 4; ++q) {
        const int r = row0 + wm + m * 16 + (lane >> 4) * 4 + q;
        const int c = n0 + wn + n * 16 + (lane & 15);
        const float h1 = acc1[m][n][q];
        const float h2 = acc2[m][n][q];
        const float act = h1 * h2 / (1.0f + __expf(-h1));
        ((__bf16*)Hact)[(size_t)r * halfsz + c] = (__bf16)act;
      }
}

// ---------------- GEMM2: out += weight * (act @ W3-slice), f32 atomic scatter ----------------
__global__ __launch_bounds__(256, 2) void gemm2_kernel(
    const unsigned short* __restrict__ Hact,
    const float* __restrict__ ew3, const float* __restrict__ sw3,
    const int2* __restrict__ tile_desc, const int* __restrict__ ntiles_g,
    const int* __restrict__ row_src, const float* __restrict__ rows_weight,
    float* __restrict__ out, int h, int halfsz)
{
  if ((int)blockIdx.x >= *ntiles_g) return;
  const int2 td = tile_desc[blockIdx.x];
  const int row0 = td.x;
  const int e = td.y;
  const int n0 = blockIdx.y * BN;
  const int ko = h * halfsz;            // global FF row offset of this slice
  const float* b3;
  const size_t ldb = DM;
  if (e < 8) b3 = ew3 + (size_t)e * DFF * DM + (size_t)ko * DM + n0;
  else       b3 = sw3 + (size_t)(ko >> 12) * SFF * DM + (size_t)(ko & 4095) * DM + n0;
  __shared__ __align__(16) char smem[32768];
  char* sA = smem;
  char* sB = smem + 16384;
  const int tid  = threadIdx.x;
  const int lane = tid & 63;
  const int wv   = tid >> 6;
  const int wm   = (wv >> 1) * 64;
  const int wn   = (wv & 1) * 64;
  const f32x4 zero = {0.f, 0.f, 0.f, 0.f};
  f32x4 acc[4][4];
  #pragma unroll
  for (int i = 0; i < 4; ++i)
    #pragma unroll
    for (int j = 0; j < 4; ++j) acc[i][j] = zero;

  const unsigned short* Arow = Hact + (size_t)row0 * halfsz;
  const int aa = lane;
  const int kg = wv;
  const int nkt = halfsz / BK;

  for (int kt = 0; kt < nkt; ++kt) {
    const int k0 = kt * BK;
    __syncthreads();
    #pragma unroll
    for (int it = 0; it < 4; ++it) {
      const int idx = it * 256 + tid;
      const int row = idx >> 3;
      const int s   = idx & 7;
      const int kb  = s ^ (row & 7);
      gload_lds16(Arow + (size_t)row * halfsz + k0 + kb * 8, sA + idx * 16);
    }
    {
      const float* p = b3 + (size_t)(k0 + kg * 16) * ldb + 2 * aa;
      float2 v[16];
      #pragma unroll
      for (int j = 0; j < 16; ++j) v[j] = *(const float2*)(p + (size_t)j * ldb);
      #pragma unroll
      for (int b = 0; b < 2; ++b) {
        #pragma unroll
        for (int no = 0; no < 2; ++no) {
          const int n  = 2 * aa + no;
          const int kb = kg * 2 + b;
          const int s  = kb ^ ((n >> 1) & 7);
          unsigned int qq[4];
          #pragma unroll
          for (int q = 0; q < 4; ++q) {
            const int j = b * 8 + 2 * q;
            qq[q] = no ? pack2(v[j].y, v[j + 1].y) : pack2(v[j].x, v[j + 1].x);
          }
          u32x4 t = {qq[0], qq[1], qq[2], qq[3]};
          *(u32x4*)(sB + n * 128 + s * 16) = t;
        }
      }
    }
    __syncthreads();
    #pragma unroll
    for (int ks = 0; ks < 2; ++ks) {
      bf16x8 af[4], bf[4];
      const int kb = ks * 4 + (lane >> 4);
      #pragma unroll
      for (int m = 0; m < 4; ++m) {
        const int r = wm + m * 16 + (lane & 15);
        af[m] = *(const bf16x8*)(sA + r * 128 + (kb ^ (r & 7)) * 16);
      }
      #pragma unroll
      for (int n = 0; n < 4; ++n) {
        const int c = wn + n * 16 + (lane & 15);
        bf[n] = *(const bf16x8*)(sB + c * 128 + (kb ^ ((c >> 1) & 7)) * 16);
      }
      #pragma unroll
      for (int m = 0; m < 4; ++m)
        #pragma unroll
        for (int n = 0; n < 4; ++n)
          acc[m][n] = __builtin_amdgcn_mfma_f32_16x16x32_bf16(af[m], bf[n], acc[m][n], 0, 0, 0);
    }
  }
  // epilogue: scale by combine weight, atomic scatter-add into out
  #pragma unroll
  for (int m = 0; m < 4; ++m)
    #pragma unroll
    for (int q = 0; q < 4; ++q) {
      const int r = row0 + wm + m * 16 + (lane >> 4) * 4 + q;
      const int tok = row_src[r];
      if (tok < 0) continue;
      const float w = rows_weight[r];
      float* orow = out + (size_t)tok * DM + n0 + wn + (lane & 15);
      #pragma unroll
      for (int n = 0; n < 4; ++n)
        atomicAdd(orow + n * 16, acc[m][n][q] * w);
    }
}

// ---------------- launch ----------------
extern "C" void kernel_launch(void* const* d_in, const int* in_sizes, int n_in,
                              void* d_out, int out_size, void* d_ws, size_t ws_size,
                              hipStream_t stream) {
  const float* x   = (const float*)d_in[0];
  const float* wg  = (const float*)d_in[1];
  const float* ew1 = (const float*)d_in[2];
  const float* ew2 = (const float*)d_in[3];
  const float* ew3 = (const float*)d_in[4];
  const float* sw1 = (const float*)d_in[5];
  const float* sw2 = (const float*)d_in[6];
  const float* sw3 = (const float*)d_in[7];
  float* out = (float*)d_out;
  char* ws = (char*)d_ws;

  int*   cursor     = (int*)(ws + 0);
  int*   ntiles_g   = (int*)(ws + 64);
  float* scores_buf = (float*)(ws + 256);
  float* lse_buf    = (float*)(ws + 256 + 131072);
  int*   bucket_tok = (int*)(ws + 147712);
  float* bucket_w   = (float*)(ws + 278784);
  int2*  tile_desc  = (int2*)(ws + 409856);
  int*   row_src    = (int*)(ws + 411904);
  float* rows_w     = (float*)(ws + 465152);
  unsigned short* Xg = (unsigned short*)(ws + (1u << 20));
  const size_t xg_end = (1u << 20) + (size_t)MAXROWS * DM * 2;
  unsigned short* Hact = (unsigned short*)(ws + xg_end);

  // pick largest FF slice whose act buffer fits the workspace
  int halfsz = 512;
  for (int cand = 4096; cand >= 512; cand >>= 1)
    if (xg_end + (size_t)MAXROWS * (size_t)cand * 2 <= ws_size) { halfsz = cand; break; }

  hipMemsetAsync(ws, 0, 256, stream);
  hipMemsetAsync(d_out, 0, (size_t)out_size * sizeof(float), stream);
  router_kernel<<<T_TOK / 4, 256, 0, stream>>>(x, wg, scores_buf, lse_buf, bucket_tok, bucket_w, cursor);
  plan_kernel<<<1, 256, 0, stream>>>(scores_buf, lse_buf, cursor, bucket_tok, bucket_w,
                                     tile_desc, ntiles_g, row_src, rows_w, out + (size_t)T_TOK * DM);
  gather_kernel<<<MAXROWS, 256, 0, stream>>>(x, row_src, Xg);
  const int npass = DFF / halfsz;
  for (int h = 0; h < npass; ++h) {
    gemm1_kernel<<<dim3(MAXTILES, halfsz / BN), 256, 0, stream>>>(
        Xg, ew1, ew2, sw1, sw2, tile_desc, ntiles_g, Hact, h, halfsz);
    gemm2_kernel<<<dim3(MAXTILES, DM / BN), 256, 0, stream>>>(
        Hact, ew3, sw3, tile_desc, ntiles_g, row_src, rows_w, out, h, halfsz);
  }
}